// Round 13
// baseline (195.977 us; speedup 1.0000x reference)
//
#include <hip/hip_runtime.h>
#include <math.h>

typedef __attribute__((ext_vector_type(8))) short short8;
typedef __attribute__((ext_vector_type(4))) float f32x4;

__device__ __forceinline__ unsigned short f2bf(float f) {
    unsigned int u; __builtin_memcpy(&u, &f, 4);
    unsigned int r = (u + 0x7FFFu + ((u >> 16) & 1u)) >> 16;
    return (unsigned short)r;
}
__device__ __forceinline__ float bf2f(unsigned short h) {
    unsigned int u = ((unsigned int)h) << 16;
    float f; __builtin_memcpy(&f, &u, 4); return f;
}
__device__ __forceinline__ void gl2lds16(const unsigned short* g, unsigned short* l) {
    __builtin_amdgcn_global_load_lds(
        (const __attribute__((address_space(1))) unsigned int*)g,
        (__attribute__((address_space(3))) unsigned int*)l, 16, 0, 0);
}

// ---------------------------------------------------------------------------
// bf16 MFMA GEMM: tile 128x128, BK=64, 8 waves, counted-vmcnt double buffer,
// XOR-chunk swizzle (chunk c of row r at slot c^(r&7); staged pre-swizzled).
// AF32: A operand is f32 in global; reg-staged (float4 loads -> f2bf ->
//       swizzled ds_write_b128). Same swizzle key -> read side unchanged.
//       Only B's 2 gl2lds16 count in vmcnt; lgkmcnt(0) drains the ds_writes.
// T5: s_setprio(1) around the MFMA cluster (wave role diversity exists via
//     the counted-vmcnt stagger).
// Wave w (wr=w>>2, wc=w&3) owns a 64x32 output sub-tile: acc[4][2].
// STATS: also emit per-block (sum, sumsq) fp32 partials for InstanceNorm.
// ---------------------------------------------------------------------------
template<typename OutT, bool STATS, bool AF32>
__global__ __launch_bounds__(512, 4)
void gemm_bt(const void* __restrict__ Ain, const unsigned short* __restrict__ B,
             OutT* __restrict__ C, float2* __restrict__ sp_out,
             int K, long lda, long ldb, long ldc,
             long sa_bb, long sa_bh, long sb_bb, long sb_bh, long sc_z,
             int H, float alpha)
{
    __shared__ unsigned short As[2][128 * 64];
    __shared__ unsigned short Bs[2][128 * 64];

    const int z = blockIdx.z;
    const int bb = z / H, hh = z - bb * H;
    const unsigned short* A = AF32 ? nullptr
        : (const unsigned short*)Ain + (long)bb * sa_bb + (long)hh * sa_bh;
    const float* Af = AF32 ? (const float*)Ain + (long)bb * sa_bb + (long)hh * sa_bh
                           : nullptr;
    B += (long)bb * sb_bb + (long)hh * sb_bh;
    C += (long)z * sc_z;

    const int tid  = threadIdx.x;
    const int lane = tid & 63;
    const int wave = tid >> 6;           // 0..7
    const int wr = wave >> 2, wc = wave & 3;

    const long m0 = (long)blockIdx.y * 128;
    const long n0 = (long)blockIdx.x * 128;

    // ---- bf16 A/B staging (gl2lds16, pre-swizzled global k-chunk) ----
    const int lrow = lane >> 3;                            // 0..7
    const int kc   = ((lane & 7) ^ (lrow & 7)) * 8;        // swizzled k elem
    const unsigned short* ga0 = AF32 ? nullptr : A + (m0 + wave * 16 + lrow) * lda + kc;
    const unsigned short* ga1 = AF32 ? nullptr : ga0 + 8 * lda;
    const unsigned short* gb0 = B + (n0 + wave * 16 + lrow) * ldb + kc;
    const unsigned short* gb1 = gb0 + 8 * ldb;

    // ---- AF32 A staging: row = wave*16 + (lane>>2), lane&3 = kv quarter ----
    const int arow = lane >> 2;                            // 0..15
    const int aq   = lane & 3;                             // 16 kv each
    const float* gaf = AF32 ? Af + (m0 + wave * 16 + arow) * lda + aq * 16 : nullptr;
    unsigned short* al_base = &As[0][0];

    auto stg = [&](int buf, long koff) {
        if constexpr (AF32) {
            const float* src = gaf + koff;
            float4 v0 = *(const float4*)(src);
            float4 v1 = *(const float4*)(src + 4);
            float4 v2 = *(const float4*)(src + 8);
            float4 v3 = *(const float4*)(src + 12);
            short8 c0, c1;
            c0[0] = (short)f2bf(v0.x); c0[1] = (short)f2bf(v0.y);
            c0[2] = (short)f2bf(v0.z); c0[3] = (short)f2bf(v0.w);
            c0[4] = (short)f2bf(v1.x); c0[5] = (short)f2bf(v1.y);
            c0[6] = (short)f2bf(v1.z); c0[7] = (short)f2bf(v1.w);
            c1[0] = (short)f2bf(v2.x); c1[1] = (short)f2bf(v2.y);
            c1[2] = (short)f2bf(v2.z); c1[3] = (short)f2bf(v2.w);
            c1[4] = (short)f2bf(v3.x); c1[5] = (short)f2bf(v3.y);
            c1[6] = (short)f2bf(v3.z); c1[7] = (short)f2bf(v3.w);
            const int row = wave * 16 + arow;
            const int s0 = (aq * 2) ^ (arow & 7);
            const int s1 = (aq * 2 + 1) ^ (arow & 7);
            unsigned short* dst = &As[buf][row * 64];
            *(short8*)(dst + s0 * 8) = c0;
            *(short8*)(dst + s1 * 8) = c1;
        } else {
            gl2lds16(ga0 + koff, &As[buf][wave * 1024]);
            gl2lds16(ga1 + koff, &As[buf][wave * 1024 + 512]);
        }
        gl2lds16(gb0 + koff, &Bs[buf][wave * 1024]);
        gl2lds16(gb1 + koff, &Bs[buf][wave * 1024 + 512]);
    };

    const int fr = lane & 15;
    const int hi = lane >> 4;            // 0..3
    const int sw = fr & 7;               // read-side swizzle key

    f32x4 acc[4][2];
    const f32x4 zero4 = {0.f, 0.f, 0.f, 0.f};
    #pragma unroll
    for (int i = 0; i < 4; ++i)
        #pragma unroll
        for (int j = 0; j < 2; ++j) acc[i][j] = zero4;

    stg(0, 0);
    stg(1, 64);

    int cur = 0;
    for (long k0 = 0; k0 < K; k0 += 64) {
        if (k0 + 64 < K) {
            if constexpr (AF32) asm volatile("s_waitcnt vmcnt(2) lgkmcnt(0)" ::: "memory");
            else                asm volatile("s_waitcnt vmcnt(4)" ::: "memory");
        } else {
            asm volatile("s_waitcnt vmcnt(0) lgkmcnt(0)" ::: "memory");
        }
        __builtin_amdgcn_s_barrier();    // buf[cur] landed for all waves

        __builtin_amdgcn_s_setprio(1);
        #pragma unroll
        for (int kk = 0; kk < 2; ++kk) {
            short8 af[4], bfr[2];
            #pragma unroll
            for (int i = 0; i < 4; ++i) {
                const int row = wr * 64 + i * 16 + fr;
                af[i] = *(const short8*)(&As[cur][row * 64 + (((kk * 4 + hi) ^ sw) * 8)]);
            }
            #pragma unroll
            for (int j = 0; j < 2; ++j) {
                const int row = wc * 32 + j * 16 + fr;
                bfr[j] = *(const short8*)(&Bs[cur][row * 64 + (((kk * 4 + hi) ^ sw) * 8)]);
            }
            #pragma unroll
            for (int i = 0; i < 4; ++i)
                #pragma unroll
                for (int j = 0; j < 2; ++j)
                    acc[i][j] = __builtin_amdgcn_mfma_f32_16x16x32_bf16(af[i], bfr[j], acc[i][j], 0, 0, 0);
        }
        __builtin_amdgcn_s_setprio(0);

        asm volatile("s_waitcnt lgkmcnt(0)" ::: "memory");
        __builtin_amdgcn_s_barrier();    // all waves done reading buf[cur]
        if (k0 + 128 < K) stg(cur, k0 + 128);
        cur ^= 1;
    }

    float s = 0.f, s2 = 0.f;
    const int orow = hi * 4;
    #pragma unroll
    for (int i = 0; i < 4; ++i) {
        const long rbase = m0 + wr * 64 + i * 16 + orow;
        #pragma unroll
        for (int j = 0; j < 2; ++j) {
            const long cidx = n0 + wc * 32 + j * 16 + fr;
            f32x4 v = acc[i][j];
            #pragma unroll
            for (int q = 0; q < 4; ++q) {
                float val = alpha * v[q];
                if constexpr (STATS) { s += val; s2 += val * val; }
                if constexpr (sizeof(OutT) == 4) C[(rbase + q) * ldc + cidx] = val;
                else                             C[(rbase + q) * ldc + cidx] = f2bf(val);
            }
        }
    }

    if constexpr (STATS) {
        float* red = (float*)al_base;
        red[tid] = s; red[512 + tid] = s2;
        __syncthreads();
        for (int off = 256; off > 0; off >>= 1) {
            if (tid < off) { red[tid] += red[tid + off]; red[512 + tid] += red[512 + tid + off]; }
            __syncthreads();
        }
        if (tid == 0)
            sp_out[(long)z * 32 + blockIdx.y * gridDim.x + blockIdx.x] =
                make_float2(red[0], red[512]);
    }
}

// ---------------------------------------------------------------------------
// 64x64 transpose-cast worker, LDS-vectorized.
// ---------------------------------------------------------------------------
__device__ __forceinline__
void tc64_impl(const float* __restrict__ in, unsigned short* __restrict__ outT,
               int R, int Cin, long ldaT, int bx, int by, unsigned short (*t)[68])
{
    const int r0 = bx * 64, c0 = by * 64;
    const int tid = threadIdx.x;
    const int rr  = tid >> 4;          // 0..15
    const int cc4 = (tid & 15) * 4;    // 0..60
    const bool real = (c0 + cc4) < Cin;

    #pragma unroll
    for (int i = 0; i < 4; ++i) {
        const int r = rr + i * 16;
        float4 v = make_float4(0.f, 0.f, 0.f, 0.f);
        if (real) v = *(const float4*)(in + (long)(r0 + r) * Cin + c0 + cc4);
        ushort4 o;
        o.x = f2bf(v.x); o.y = f2bf(v.y); o.z = f2bf(v.z); o.w = f2bf(v.w);
        *(ushort4*)&t[r][cc4] = o;
    }
    __syncthreads();
    #pragma unroll
    for (int i = 0; i < 2; ++i) {
        const int p = rr + i * 16;      // 0..31 -> out-row pair (2p, 2p+1)
        const int c = 2 * p;
        ushort2 a0 = *(const ushort2*)&t[cc4 + 0][c];
        ushort2 a1 = *(const ushort2*)&t[cc4 + 1][c];
        ushort2 a2 = *(const ushort2*)&t[cc4 + 2][c];
        ushort2 a3 = *(const ushort2*)&t[cc4 + 3][c];
        ushort4 w0; w0.x = a0.x; w0.y = a1.x; w0.z = a2.x; w0.w = a3.x;
        ushort4 w1; w1.x = a0.y; w1.y = a1.y; w1.z = a2.y; w1.w = a3.y;
        *(ushort4*)(outT + (long)(c0 + c) * ldaT + r0 + cc4)     = w0;
        *(ushort4*)(outT + (long)(c0 + c + 1) * ldaT + r0 + cc4) = w1;
    }
}

// ---------------------------------------------------------------------------
// ALL preps in one launch (block-range segmented). emb_allB eliminated.
// ---------------------------------------------------------------------------
__global__ __launch_bounds__(256)
void prep_all(const float* __restrict__ emb, const float* __restrict__ emb_all,
              const float* __restrict__ Wq, const float* __restrict__ Wk,
              const float* __restrict__ Wv, const float* __restrict__ Wo,
              unsigned short* __restrict__ embT, unsigned short* __restrict__ emb_allT,
              unsigned short* __restrict__ WqB, unsigned short* __restrict__ WkB,
              unsigned short* __restrict__ WvT, unsigned short* __restrict__ WoB)
{
    __shared__ unsigned short t[64][68];
    int bid = blockIdx.x;
    if (bid < 4096) {
        const int z = bid >> 10, r2 = bid & 1023, by = r2 >> 6, bx = r2 & 63;
        tc64_impl(emb_all + (long)z * 4096 * 960, emb_allT + (long)z * 1024 * 4096,
                  4096, 960, 4096, bx, by, t);
        return;
    }
    bid -= 4096;
    if (bid < 2048) {
        const int z = bid >> 9, r2 = bid & 511, by = r2 >> 6, bx = r2 & 63;
        tc64_impl(emb + (long)z * 4096 * 512, embT + (long)z * 512 * 4096,
                  4096, 512, 4096, bx, by, t);
        return;
    }
    bid -= 2048;
    if (bid < 960) {
        const int z = bid / 240, r2 = bid % 240, by = r2 / 15, bx = r2 % 15;
        tc64_impl(Wv + (long)z * 960 * 960, WvT + (long)z * 1024 * 960,
                  960, 960, 960, bx, by, t);
        return;
    }
    bid -= 960;
    long q = (long)bid * 256 + threadIdx.x;
    if (q < 983040) {                       // WkB
        long e = q * 4;
        long h = e / 983040L; long r2 = e - h * 983040L;
        long r = r2 / 960;    long c = r2 - r * 960;
        ushort4 o = {0, 0, 0, 0};
        if (r < 960) {
            float4 v = *(const float4*)(Wk + (h * 960 + r) * 960 + c);
            o.x = f2bf(v.x); o.y = f2bf(v.y); o.z = f2bf(v.z); o.w = f2bf(v.w);
        }
        *(ushort4*)(WkB + e) = o;
        return;
    }
    q -= 983040;
    if (q < 262144) {                       // WqB
        long e = q * 4;
        float4 v = *(const float4*)(Wq + e);
        ushort4 o; o.x = f2bf(v.x); o.y = f2bf(v.y); o.z = f2bf(v.z); o.w = f2bf(v.w);
        *(ushort4*)(WqB + e) = o;
        return;
    }
    q -= 262144;
    if (q < 65536) {                        // WoB
        long e = q * 4;
        float4 v = *(const float4*)(Wo + e);
        ushort4 o; o.x = f2bf(v.x); o.y = f2bf(v.y); o.z = f2bf(v.z); o.w = f2bf(v.w);
        *(ushort4*)(WoB + e) = o;
    }
}

// GT[b][r] = f2bf(sum_sp bf16 partK[b][sp][r]); 8 elems/thread, 1024 blocks.
__global__ __launch_bounds__(256)
void reduce_gt(const unsigned short* __restrict__ part, unsigned short* __restrict__ GT)
{
    long i = ((long)blockIdx.x * 256 + threadIdx.x) * 8;
    long b = i >> 19, r = i & 524287;
    const unsigned short* p = part + b * 4 * 524288 + r;
    const short8 v0 = *(const short8*)(p);
    const short8 v1 = *(const short8*)(p + 524288);
    const short8 v2 = *(const short8*)(p + 2 * 524288);
    const short8 v3 = *(const short8*)(p + 3 * 524288);
    short8 o;
    #pragma unroll
    for (int k = 0; k < 8; ++k) {
        float s = bf2f((unsigned short)v0[k]) + bf2f((unsigned short)v1[k])
                + bf2f((unsigned short)v2[k]) + bf2f((unsigned short)v3[k]);
        o[k] = (short)f2bf(s);
    }
    *(short8*)(GT + i) = o;
}

// ---------------------------------------------------------------------------
// norm + softmax, one WAVE per row (shfl-only reductions).
// ---------------------------------------------------------------------------
__global__ __launch_bounds__(256)
void norm_softmax(const unsigned short* __restrict__ SC, const float2* __restrict__ part,
                  unsigned short* __restrict__ probs)
{
    const int lane = threadIdx.x & 63;
    const int wave = threadIdx.x >> 6;
    const long row = (long)blockIdx.x * 4 + wave;
    const int z = (int)(row >> 9);

    float2 pv = part[z * 32 + (lane & 31)];
    float a = pv.x, b = pv.y;
    #pragma unroll
    for (int off = 1; off < 32; off <<= 1) {
        a += __shfl_xor(a, off);
        b += __shfl_xor(b, off);
    }
    const float ninv = 1.f / (512.f * 960.f);
    const float mean = a * ninv;
    const float rstd = rsqrtf(b * ninv - mean * mean + 960.f * 1e-5f);

    const unsigned short* p = SC + row * 1024 + lane * 16;
    const bool act = lane < 60;
    float x[16];
    {
        const short8 w0 = *(const short8*)(p);
        const short8 w1 = *(const short8*)(p + 8);
        #pragma unroll
        for (int k = 0; k < 8; ++k) {
            x[k]     = (bf2f((unsigned short)w0[k]) - mean) * rstd;
            x[k + 8] = (bf2f((unsigned short)w1[k]) - mean) * rstd;
        }
    }
    float mx = -1e30f;
    if (act) {
        #pragma unroll
        for (int k = 0; k < 16; ++k) mx = fmaxf(mx, x[k]);
    }
    #pragma unroll
    for (int off = 1; off < 64; off <<= 1) mx = fmaxf(mx, __shfl_xor(mx, off));

    float s = 0.f;
    if (act) {
        #pragma unroll
        for (int k = 0; k < 16; ++k) { x[k] = __expf(x[k] - mx); s += x[k]; }
    }
    #pragma unroll
    for (int off = 1; off < 64; off <<= 1) s += __shfl_xor(s, off);
    const float inv = 1.f / s;

    unsigned short* o = probs + row * 1024 + lane * 16;
    short8 o0 = {0,0,0,0,0,0,0,0}, o1 = {0,0,0,0,0,0,0,0};
    if (act) {
        #pragma unroll
        for (int k = 0; k < 8; ++k) {
            o0[k] = (short)f2bf(x[k] * inv);
            o1[k] = (short)f2bf(x[k + 8] * inv);
        }
    }
    *(short8*)(o)     = o0;
    *(short8*)(o + 8) = o1;
}

// ---------------------------------------------------------------------------
// UbarT[b] = sum_h UT[b*4+h]; 8 elems/thread.
// ---------------------------------------------------------------------------
__global__ __launch_bounds__(256)
void mean_heads(const unsigned short* __restrict__ UT, unsigned short* __restrict__ Ub)
{
    const long per = 1024L * 512;
    long e = ((long)blockIdx.x * 256 + threadIdx.x) * 8;
    long b = e / per; long r = e - b * per;
    const short8 v0 = *(const short8*)(UT + (b * 4 + 0) * per + r);
    const short8 v1 = *(const short8*)(UT + (b * 4 + 1) * per + r);
    const short8 v2 = *(const short8*)(UT + (b * 4 + 2) * per + r);
    const short8 v3 = *(const short8*)(UT + (b * 4 + 3) * per + r);
    short8 o;
    #pragma unroll
    for (int k = 0; k < 8; ++k) {
        float s = bf2f((unsigned short)v0[k]) + bf2f((unsigned short)v1[k])
                + bf2f((unsigned short)v2[k]) + bf2f((unsigned short)v3[k]);
        o[k] = (short)f2bf(s);
    }
    *(short8*)(Ub + b * per + r) = o;
}

// ---------------------------------------------------------------------------
extern "C" void kernel_launch(void* const* d_in, const int* in_sizes, int n_in,
                              void* d_out, int out_size, void* d_ws, size_t ws_size,
                              hipStream_t stream)
{
    const float* emb     = (const float*)d_in[0];  // [4][4096][512]
    const float* emb_all = (const float*)d_in[1];  // [4][4096][960]
    const float* Wq      = (const float*)d_in[2];  // [4][512][512]
    const float* Wk      = (const float*)d_in[3];  // [4][960][960]
    const float* Wv      = (const float*)d_in[4];  // [4][960][960]
    const float* Wo      = (const float*)d_in[5];  // [512][512]
    float* out = (float*)d_out;

    char* ws = (char*)d_ws;
    unsigned short* embT     = (unsigned short*)(ws);              // [b][512][4096]
    unsigned short* emb_allT = (unsigned short*)(ws + 16777216);   // [b][1024][4096]
    unsigned short* WqB      = (unsigned short*)(ws + 81788928);   // [h][512][512]
    unsigned short* WkB      = (unsigned short*)(ws + 83886080);   // [h][1024][960]
    unsigned short* WvT      = (unsigned short*)(ws + 91750400);   // [h][1024][960]
    unsigned short* WoB      = (unsigned short*)(ws + 99614720);   // [512][512]
    unsigned short* GT       = (unsigned short*)(ws + 100139008);  // [b][1024][512]
    unsigned short* probs    = (unsigned short*)(ws + 104333312);  // [z][512][1024]
    float2* sc_part          = (float2*)(ws + 121110528);          // [16][32]
    unsigned short* partK    = (unsigned short*)(ws + 134217728);  // 16 MB bf16

    // region reuse (sequential liveness)
    unsigned short* S1  = embT;                             // embT dead after splitk
    unsigned short* SC  = emb_allT;                         // emb_allT dead after splitk
    unsigned short* UT  = (unsigned short*)(ws + 33554432); // 2nd half of emb_allT region
    unsigned short* UbT = GT;                               // GT dead after step 2
    unsigned short* W2  = embT;                             // S1 dead after step 3

    // ---- 0. all preps, one launch ----
    prep_all<<<12224, 256, 0, stream>>>(emb, emb_all, Wq, Wk, Wv, Wo,
                                        embT, emb_allT, WqB, WkB, WvT, WoB);

    // ---- 1. split-K (z = b*4+sp): partK[z] = emb_allT chunk x embT chunk^T ----
    gemm_bt<unsigned short, false, false><<<dim3(4, 8, 16), 512, 0, stream>>>(
        emb_allT, embT, partK, nullptr, 1024, 4096, 4096, 512,
        1024L*4096, 1024, 512L*4096, 1024, 1024L*512, 4, 1.f);
    reduce_gt<<<1024, 256, 0, stream>>>(partK, GT);

    // ---- 2. S1[b,h] = Wq[h] x GT[b]^T  (M=512, N=1024, K=512) ----
    gemm_bt<unsigned short, false, false><<<dim3(8, 4, 16), 512, 0, stream>>>(
        WqB, GT, S1, nullptr, 512, 512, 512, 1024,
        0, 512L*512, 1024L*512, 0, 512L*1024, 4, 1.f);

    // ---- 3. SC[z] = S1[z] x WkB[h]^T (bf16 out) + fused stats partials ----
    gemm_bt<unsigned short, true, false><<<dim3(8, 4, 16), 512, 0, stream>>>(
        S1, WkB, SC, sc_part, 960, 1024, 960, 1024,
        4L*512*1024, 512L*1024, 0, 1024L*960, 512L*1024, 4, 1.f);

    // ---- 4. fused instance-norm + softmax (wave-per-row) ----
    norm_softmax<<<2048, 256, 0, stream>>>(SC, sc_part, probs);

    // ---- 5. UT[z] = WvT[h] x probs[z]^T * 0.25  (M=1024, N=512, K=960) ----
    gemm_bt<unsigned short, false, false><<<dim3(4, 8, 16), 512, 0, stream>>>(
        WvT, probs, UT, nullptr, 960, 960, 1024, 512,
        0, 1024L*960, 4L*512*1024, 512L*1024, 1024L*512, 4, 0.25f);

    // ---- 6. UbT[b] = sum_h UT[b,h] ----
    mean_heads<<<1024, 256, 0, stream>>>(UT, UbT);

    // ---- 7. W2[b] = WoB x UbT[b]^T  (M=512, N=1024, K=512) ----
    gemm_bt<unsigned short, false, false><<<dim3(8, 4, 4), 512, 0, stream>>>(
        WoB, UbT, W2, nullptr, 512, 512, 512, 1024,
        0, 0, 1024L*512, 0, 512L*1024, 1, 1.f);

    // ---- 8. out[b] = emb_all[b](f32, reg-staged) x W2[b]^T  (M=4096,N=512,K=960) ----
    gemm_bt<float, false, true><<<dim3(4, 32, 4), 512, 0, stream>>>(
        emb_all, W2, out, nullptr, 960, 960, 1024, 512,
        4096L*960, 0, 512L*1024, 0, 4096L*512, 1, 1.f);
}

// Round 14
// 186.741 us; speedup vs baseline: 1.0495x; 1.0495x over previous
//
#include <hip/hip_runtime.h>
#include <math.h>

typedef __attribute__((ext_vector_type(8))) short short8;
typedef __attribute__((ext_vector_type(4))) float f32x4;

__device__ __forceinline__ unsigned short f2bf(float f) {
    unsigned int u; __builtin_memcpy(&u, &f, 4);
    unsigned int r = (u + 0x7FFFu + ((u >> 16) & 1u)) >> 16;
    return (unsigned short)r;
}
__device__ __forceinline__ float bf2f(unsigned short h) {
    unsigned int u = ((unsigned int)h) << 16;
    float f; __builtin_memcpy(&f, &u, 4); return f;
}
__device__ __forceinline__ void gl2lds16(const unsigned short* g, unsigned short* l) {
    __builtin_amdgcn_global_load_lds(
        (const __attribute__((address_space(1))) unsigned int*)g,
        (__attribute__((address_space(3))) unsigned int*)l, 16, 0, 0);
}

// ---------------------------------------------------------------------------
// bf16 MFMA GEMM: tile 128x128, BK=64, 8 waves, counted-vmcnt double buffer.
// XOR-chunk swizzle: chunk c of row r lives at slot c^(r&7); staging lane
// pre-swizzles its global source chunk (both-sides rule), fragment read XORs
// with fr&7. No bank conflicts on ds_read_b128.
//   loop: vmcnt(4|0) ; s_barrier ; [2 x (6 ds_read_b128 + 8 MFMA)] ;
//         lgkmcnt(0) ; s_barrier ; restage (2 tiles ahead)
// Wave w (wr=w>>2, wc=w&3) owns a 64x32 output sub-tile: acc[4][2].
// STATS: also emit per-block (sum, sumsq) fp32 partials for InstanceNorm.
// ---------------------------------------------------------------------------
template<typename OutT, bool STATS>
__global__ __launch_bounds__(512, 4)
void gemm_bt(const unsigned short* __restrict__ A, const unsigned short* __restrict__ B,
             OutT* __restrict__ C, float2* __restrict__ sp_out,
             int K, long lda, long ldb, long ldc,
             long sa_bb, long sa_bh, long sb_bb, long sb_bh, long sc_z,
             int H, float alpha)
{
    __shared__ unsigned short As[2][128 * 64];
    __shared__ unsigned short Bs[2][128 * 64];

    const int z = blockIdx.z;
    const int bb = z / H, hh = z - bb * H;
    A += (long)bb * sa_bb + (long)hh * sa_bh;
    B += (long)bb * sb_bb + (long)hh * sb_bh;
    C += (long)z * sc_z;

    const int tid  = threadIdx.x;
    const int lane = tid & 63;
    const int wave = tid >> 6;           // 0..7
    const int wr = wave >> 2, wc = wave & 3;

    const long m0 = (long)blockIdx.y * 128;
    const long n0 = (long)blockIdx.x * 128;

    // staging: wave stages 16 rows x 64 k per operand as two 8-row chunks.
    const int lrow = lane >> 3;                            // 0..7
    const int kc   = ((lane & 7) ^ (lrow & 7)) * 8;        // swizzled k elem
    const unsigned short* ga0 = A + (m0 + wave * 16 + lrow) * lda + kc;
    const unsigned short* ga1 = ga0 + 8 * lda;
    const unsigned short* gb0 = B + (n0 + wave * 16 + lrow) * ldb + kc;
    const unsigned short* gb1 = gb0 + 8 * ldb;

    auto stg = [&](int buf, long koff) {
        gl2lds16(ga0 + koff, &As[buf][wave * 1024]);
        gl2lds16(ga1 + koff, &As[buf][wave * 1024 + 512]);
        gl2lds16(gb0 + koff, &Bs[buf][wave * 1024]);
        gl2lds16(gb1 + koff, &Bs[buf][wave * 1024 + 512]);
    };

    const int fr = lane & 15;
    const int hi = lane >> 4;            // 0..3
    const int sw = fr & 7;               // read-side swizzle key

    f32x4 acc[4][2];
    const f32x4 zero4 = {0.f, 0.f, 0.f, 0.f};
    #pragma unroll
    for (int i = 0; i < 4; ++i)
        #pragma unroll
        for (int j = 0; j < 2; ++j) acc[i][j] = zero4;

    // prologue: two stages in flight (8 loads/wave)
    stg(0, 0);
    stg(1, 64);

    int cur = 0;
    for (long k0 = 0; k0 < K; k0 += 64) {
        if (k0 + 64 < K) {
            asm volatile("s_waitcnt vmcnt(4)" ::: "memory");
        } else {
            asm volatile("s_waitcnt vmcnt(0)" ::: "memory");
        }
        __builtin_amdgcn_s_barrier();    // buf[cur] landed for all waves

        #pragma unroll
        for (int kk = 0; kk < 2; ++kk) {
            short8 af[4], bfr[2];
            #pragma unroll
            for (int i = 0; i < 4; ++i) {
                const int row = wr * 64 + i * 16 + fr;
                af[i] = *(const short8*)(&As[cur][row * 64 + (((kk * 4 + hi) ^ sw) * 8)]);
            }
            #pragma unroll
            for (int j = 0; j < 2; ++j) {
                const int row = wc * 32 + j * 16 + fr;
                bfr[j] = *(const short8*)(&Bs[cur][row * 64 + (((kk * 4 + hi) ^ sw) * 8)]);
            }
            #pragma unroll
            for (int i = 0; i < 4; ++i)
                #pragma unroll
                for (int j = 0; j < 2; ++j)
                    acc[i][j] = __builtin_amdgcn_mfma_f32_16x16x32_bf16(af[i], bfr[j], acc[i][j], 0, 0, 0);
        }

        asm volatile("s_waitcnt lgkmcnt(0)" ::: "memory");
        __builtin_amdgcn_s_barrier();    // all waves done reading buf[cur]
        if (k0 + 128 < K) stg(cur, k0 + 128);
        cur ^= 1;
    }

    float s = 0.f, s2 = 0.f;
    const int orow = hi * 4;
    #pragma unroll
    for (int i = 0; i < 4; ++i) {
        const long rbase = m0 + wr * 64 + i * 16 + orow;
        #pragma unroll
        for (int j = 0; j < 2; ++j) {
            const long cidx = n0 + wc * 32 + j * 16 + fr;
            f32x4 v = acc[i][j];
            #pragma unroll
            for (int q = 0; q < 4; ++q) {
                float val = alpha * v[q];
                if constexpr (STATS) { s += val; s2 += val * val; }
                if constexpr (sizeof(OutT) == 4) C[(rbase + q) * ldc + cidx] = val;
                else                             C[(rbase + q) * ldc + cidx] = f2bf(val);
            }
        }
    }

    if constexpr (STATS) {
        float* red = (float*)&As[0][0];
        red[tid] = s; red[512 + tid] = s2;
        __syncthreads();
        for (int off = 256; off > 0; off >>= 1) {
            if (tid < off) { red[tid] += red[tid + off]; red[512 + tid] += red[512 + tid + off]; }
            __syncthreads();
        }
        if (tid == 0)
            sp_out[(long)z * 32 + blockIdx.y * gridDim.x + blockIdx.x] =
                make_float2(red[0], red[512]);
    }
}

// ---------------------------------------------------------------------------
// 64x64 transpose-cast worker, LDS-vectorized; outT row pitch = ldaT.
// ---------------------------------------------------------------------------
__device__ __forceinline__
void tc64_impl(const float* __restrict__ in, unsigned short* __restrict__ outT,
               unsigned short* __restrict__ outB, int R, int Cin, long ldaT,
               int bx, int by, bool dual, unsigned short (*t)[68])
{
    const int r0 = bx * 64, c0 = by * 64;
    const int tid = threadIdx.x;
    const int rr  = tid >> 4;          // 0..15
    const int cc4 = (tid & 15) * 4;    // 0..60
    const bool real = (c0 + cc4) < Cin;

    #pragma unroll
    for (int i = 0; i < 4; ++i) {
        const int r = rr + i * 16;
        float4 v = make_float4(0.f, 0.f, 0.f, 0.f);
        if (real) v = *(const float4*)(in + (long)(r0 + r) * Cin + c0 + cc4);
        ushort4 o;
        o.x = f2bf(v.x); o.y = f2bf(v.y); o.z = f2bf(v.z); o.w = f2bf(v.w);
        *(ushort4*)&t[r][cc4] = o;
        if (dual && real)
            *(ushort4*)(outB + (long)(r0 + r) * Cin + c0 + cc4) = o;
    }
    __syncthreads();
    #pragma unroll
    for (int i = 0; i < 2; ++i) {
        const int p = rr + i * 16;      // 0..31 -> out-row pair (2p, 2p+1)
        const int c = 2 * p;
        ushort2 a0 = *(const ushort2*)&t[cc4 + 0][c];
        ushort2 a1 = *(const ushort2*)&t[cc4 + 1][c];
        ushort2 a2 = *(const ushort2*)&t[cc4 + 2][c];
        ushort2 a3 = *(const ushort2*)&t[cc4 + 3][c];
        ushort4 w0; w0.x = a0.x; w0.y = a1.x; w0.z = a2.x; w0.w = a3.x;
        ushort4 w1; w1.x = a0.y; w1.y = a1.y; w1.z = a2.y; w1.w = a3.y;
        *(ushort4*)(outT + (long)(c0 + c) * ldaT + r0 + cc4)     = w0;
        *(ushort4*)(outT + (long)(c0 + c + 1) * ldaT + r0 + cc4) = w1;
    }
}

// ---------------------------------------------------------------------------
// ALL preps in one launch (block-range segmented).
// ---------------------------------------------------------------------------
__global__ __launch_bounds__(256)
void prep_all(const float* __restrict__ emb, const float* __restrict__ emb_all,
              const float* __restrict__ Wq, const float* __restrict__ Wk,
              const float* __restrict__ Wv, const float* __restrict__ Wo,
              unsigned short* __restrict__ embT, unsigned short* __restrict__ emb_allT,
              unsigned short* __restrict__ emb_allB, unsigned short* __restrict__ WqB,
              unsigned short* __restrict__ WkB, unsigned short* __restrict__ WvT,
              unsigned short* __restrict__ WoB)
{
    __shared__ unsigned short t[64][68];
    int bid = blockIdx.x;
    if (bid < 4096) {
        const int z = bid >> 10, r2 = bid & 1023, by = r2 >> 6, bx = r2 & 63;
        tc64_impl(emb_all + (long)z * 4096 * 960, emb_allT + (long)z * 1024 * 4096,
                  emb_allB + (long)z * 4096 * 960, 4096, 960, 4096, bx, by, true, t);
        return;
    }
    bid -= 4096;
    if (bid < 2048) {
        const int z = bid >> 9, r2 = bid & 511, by = r2 >> 6, bx = r2 & 63;
        tc64_impl(emb + (long)z * 4096 * 512, embT + (long)z * 512 * 4096,
                  nullptr, 4096, 512, 4096, bx, by, false, t);
        return;
    }
    bid -= 2048;
    if (bid < 960) {
        const int z = bid / 240, r2 = bid % 240, by = r2 / 15, bx = r2 % 15;
        tc64_impl(Wv + (long)z * 960 * 960, WvT + (long)z * 1024 * 960,
                  nullptr, 960, 960, 960, bx, by, false, t);
        return;
    }
    bid -= 960;
    long q = (long)bid * 256 + threadIdx.x;
    if (q < 983040) {                       // WkB
        long e = q * 4;
        long h = e / 983040L; long r2 = e - h * 983040L;
        long r = r2 / 960;    long c = r2 - r * 960;
        ushort4 o = {0, 0, 0, 0};
        if (r < 960) {
            float4 v = *(const float4*)(Wk + (h * 960 + r) * 960 + c);
            o.x = f2bf(v.x); o.y = f2bf(v.y); o.z = f2bf(v.z); o.w = f2bf(v.w);
        }
        *(ushort4*)(WkB + e) = o;
        return;
    }
    q -= 983040;
    if (q < 262144) {                       // WqB
        long e = q * 4;
        float4 v = *(const float4*)(Wq + e);
        ushort4 o; o.x = f2bf(v.x); o.y = f2bf(v.y); o.z = f2bf(v.z); o.w = f2bf(v.w);
        *(ushort4*)(WqB + e) = o;
        return;
    }
    q -= 262144;
    if (q < 65536) {                        // WoB
        long e = q * 4;
        float4 v = *(const float4*)(Wo + e);
        ushort4 o; o.x = f2bf(v.x); o.y = f2bf(v.y); o.z = f2bf(v.z); o.w = f2bf(v.w);
        *(ushort4*)(WoB + e) = o;
    }
}

// GT[b][r] = f2bf(sum_sp bf16 partK[b][sp][r]); 8 elems/thread, 1024 blocks.
__global__ __launch_bounds__(256)
void reduce_gt(const unsigned short* __restrict__ part, unsigned short* __restrict__ GT)
{
    long i = ((long)blockIdx.x * 256 + threadIdx.x) * 8;
    long b = i >> 19, r = i & 524287;
    const unsigned short* p = part + b * 4 * 524288 + r;
    const short8 v0 = *(const short8*)(p);
    const short8 v1 = *(const short8*)(p + 524288);
    const short8 v2 = *(const short8*)(p + 2 * 524288);
    const short8 v3 = *(const short8*)(p + 3 * 524288);
    short8 o;
    #pragma unroll
    for (int k = 0; k < 8; ++k) {
        float s = bf2f((unsigned short)v0[k]) + bf2f((unsigned short)v1[k])
                + bf2f((unsigned short)v2[k]) + bf2f((unsigned short)v3[k]);
        o[k] = (short)f2bf(s);
    }
    *(short8*)(GT + i) = o;
}

// ---------------------------------------------------------------------------
// norm + softmax, one WAVE per row (shfl-only reductions).
// ---------------------------------------------------------------------------
__global__ __launch_bounds__(256)
void norm_softmax(const unsigned short* __restrict__ SC, const float2* __restrict__ part,
                  unsigned short* __restrict__ probs)
{
    const int lane = threadIdx.x & 63;
    const int wave = threadIdx.x >> 6;
    const long row = (long)blockIdx.x * 4 + wave;
    const int z = (int)(row >> 9);

    float2 pv = part[z * 32 + (lane & 31)];
    float a = pv.x, b = pv.y;
    #pragma unroll
    for (int off = 1; off < 32; off <<= 1) {
        a += __shfl_xor(a, off);
        b += __shfl_xor(b, off);
    }
    const float ninv = 1.f / (512.f * 960.f);
    const float mean = a * ninv;
    const float rstd = rsqrtf(b * ninv - mean * mean + 960.f * 1e-5f);

    const unsigned short* p = SC + row * 1024 + lane * 16;
    const bool act = lane < 60;
    float x[16];
    {
        const short8 w0 = *(const short8*)(p);
        const short8 w1 = *(const short8*)(p + 8);
        #pragma unroll
        for (int k = 0; k < 8; ++k) {
            x[k]     = (bf2f((unsigned short)w0[k]) - mean) * rstd;
            x[k + 8] = (bf2f((unsigned short)w1[k]) - mean) * rstd;
        }
    }
    float mx = -1e30f;
    if (act) {
        #pragma unroll
        for (int k = 0; k < 16; ++k) mx = fmaxf(mx, x[k]);
    }
    #pragma unroll
    for (int off = 1; off < 64; off <<= 1) mx = fmaxf(mx, __shfl_xor(mx, off));

    float s = 0.f;
    if (act) {
        #pragma unroll
        for (int k = 0; k < 16; ++k) { x[k] = __expf(x[k] - mx); s += x[k]; }
    }
    #pragma unroll
    for (int off = 1; off < 64; off <<= 1) s += __shfl_xor(s, off);
    const float inv = 1.f / s;

    unsigned short* o = probs + row * 1024 + lane * 16;
    short8 o0 = {0,0,0,0,0,0,0,0}, o1 = {0,0,0,0,0,0,0,0};
    if (act) {
        #pragma unroll
        for (int k = 0; k < 8; ++k) {
            o0[k] = (short)f2bf(x[k] * inv);
            o1[k] = (short)f2bf(x[k + 8] * inv);
        }
    }
    *(short8*)(o)     = o0;
    *(short8*)(o + 8) = o1;
}

// ---------------------------------------------------------------------------
// UbarT[b] = sum_h UT[b*4+h]; 8 elems/thread.
// ---------------------------------------------------------------------------
__global__ __launch_bounds__(256)
void mean_heads(const unsigned short* __restrict__ UT, unsigned short* __restrict__ Ub)
{
    const long per = 1024L * 512;
    long e = ((long)blockIdx.x * 256 + threadIdx.x) * 8;
    long b = e / per; long r = e - b * per;
    const short8 v0 = *(const short8*)(UT + (b * 4 + 0) * per + r);
    const short8 v1 = *(const short8*)(UT + (b * 4 + 1) * per + r);
    const short8 v2 = *(const short8*)(UT + (b * 4 + 2) * per + r);
    const short8 v3 = *(const short8*)(UT + (b * 4 + 3) * per + r);
    short8 o;
    #pragma unroll
    for (int k = 0; k < 8; ++k) {
        float s = bf2f((unsigned short)v0[k]) + bf2f((unsigned short)v1[k])
                + bf2f((unsigned short)v2[k]) + bf2f((unsigned short)v3[k]);
        o[k] = (short)f2bf(s);
    }
    *(short8*)(Ub + b * per + r) = o;
}

// ---------------------------------------------------------------------------
extern "C" void kernel_launch(void* const* d_in, const int* in_sizes, int n_in,
                              void* d_out, int out_size, void* d_ws, size_t ws_size,
                              hipStream_t stream)
{
    const float* emb     = (const float*)d_in[0];  // [4][4096][512]
    const float* emb_all = (const float*)d_in[1];  // [4][4096][960]
    const float* Wq      = (const float*)d_in[2];  // [4][512][512]
    const float* Wk      = (const float*)d_in[3];  // [4][960][960]
    const float* Wv      = (const float*)d_in[4];  // [4][960][960]
    const float* Wo      = (const float*)d_in[5];  // [512][512]
    float* out = (float*)d_out;

    char* ws = (char*)d_ws;
    unsigned short* embT     = (unsigned short*)(ws);              // [b][512][4096]
    unsigned short* emb_allT = (unsigned short*)(ws + 16777216);   // [b][1024][4096]
    unsigned short* emb_allB = (unsigned short*)(ws + 50331648);   // [b][4096][960]
    unsigned short* WqB      = (unsigned short*)(ws + 81788928);   // [h][512][512]
    unsigned short* WkB      = (unsigned short*)(ws + 83886080);   // [h][1024][960]
    unsigned short* WvT      = (unsigned short*)(ws + 91750400);   // [h][1024][960]
    unsigned short* WoB      = (unsigned short*)(ws + 99614720);   // [512][512]
    unsigned short* GT       = (unsigned short*)(ws + 100139008);  // [b][1024][512]
    unsigned short* probs    = (unsigned short*)(ws + 104333312);  // [z][512][1024]
    float2* sc_part          = (float2*)(ws + 121110528);          // [16][32]
    unsigned short* partK    = (unsigned short*)(ws + 134217728);  // 16 MB bf16

    // region reuse (sequential liveness)
    unsigned short* S1  = embT;                             // embT dead after splitk
    unsigned short* SC  = emb_allT;                         // emb_allT dead after splitk
    unsigned short* UT  = (unsigned short*)(ws + 33554432); // 2nd half of emb_allT region
    unsigned short* UbT = GT;                               // GT dead after step 2
    unsigned short* W2  = embT;                             // S1 dead after step 3

    // ---- 0. all preps, one launch ----
    prep_all<<<12224, 256, 0, stream>>>(emb, emb_all, Wq, Wk, Wv, Wo,
                                        embT, emb_allT, emb_allB, WqB, WkB, WvT, WoB);

    // ---- 1. split-K (z = b*4+sp): partK[z] = emb_allT chunk x embT chunk^T ----
    gemm_bt<unsigned short, false><<<dim3(4, 8, 16), 512, 0, stream>>>(
        emb_allT, embT, partK, nullptr, 1024, 4096, 4096, 512,
        1024L*4096, 1024, 512L*4096, 1024, 1024L*512, 4, 1.f);
    reduce_gt<<<1024, 256, 0, stream>>>(partK, GT);

    // ---- 2. S1[b,h] = Wq[h] x GT[b]^T  (M=512, N=1024, K=512) ----
    gemm_bt<unsigned short, false><<<dim3(8, 4, 16), 512, 0, stream>>>(
        WqB, GT, S1, nullptr, 512, 512, 512, 1024,
        0, 512L*512, 1024L*512, 0, 512L*1024, 4, 1.f);

    // ---- 3. SC[z] = S1[z] x WkB[h]^T (bf16 out) + fused stats partials ----
    gemm_bt<unsigned short, true><<<dim3(8, 4, 16), 512, 0, stream>>>(
        S1, WkB, SC, sc_part, 960, 1024, 960, 1024,
        4L*512*1024, 512L*1024, 0, 1024L*960, 512L*1024, 4, 1.f);

    // ---- 4. fused instance-norm + softmax (wave-per-row) ----
    norm_softmax<<<2048, 256, 0, stream>>>(SC, sc_part, probs);

    // ---- 5. UT[z] = WvT[h] x probs[z]^T * 0.25  (M=1024, N=512, K=960) ----
    gemm_bt<unsigned short, false><<<dim3(4, 8, 16), 512, 0, stream>>>(
        WvT, probs, UT, nullptr, 960, 960, 1024, 512,
        0, 1024L*960, 4L*512*1024, 512L*1024, 1024L*512, 4, 0.25f);

    // ---- 6. UbT[b] = sum_h UT[b,h] ----
    mean_heads<<<1024, 256, 0, stream>>>(UT, UbT);

    // ---- 7. W2[b] = WoB x UbT[b]^T  (M=512, N=1024, K=512) ----
    gemm_bt<unsigned short, false><<<dim3(8, 4, 4), 512, 0, stream>>>(
        WoB, UbT, W2, nullptr, 512, 512, 512, 1024,
        0, 0, 1024L*512, 0, 512L*1024, 1, 1.f);

    // ---- 8. out[b] = emb_allB[b] x W2[b]^T  (M=4096, N=512, K=960) ----
    gemm_bt<float, false><<<dim3(4, 32, 4), 512, 0, stream>>>(
        emb_allB, W2, out, nullptr, 960, 960, 1024, 512,
        4096L*960, 0, 512L*1024, 0, 4096L*512, 1, 1.f);
}

// Round 15
// 172.891 us; speedup vs baseline: 1.1335x; 1.0801x over previous
//
#include <hip/hip_runtime.h>
#include <math.h>

typedef __attribute__((ext_vector_type(8))) short short8;
typedef __attribute__((ext_vector_type(4))) float f32x4;

__device__ __forceinline__ unsigned short f2bf(float f) {
    unsigned int u; __builtin_memcpy(&u, &f, 4);
    unsigned int r = (u + 0x7FFFu + ((u >> 16) & 1u)) >> 16;
    return (unsigned short)r;
}
__device__ __forceinline__ float bf2f(unsigned short h) {
    unsigned int u = ((unsigned int)h) << 16;
    float f; __builtin_memcpy(&f, &u, 4); return f;
}
__device__ __forceinline__ void gl2lds16(const unsigned short* g, unsigned short* l) {
    __builtin_amdgcn_global_load_lds(
        (const __attribute__((address_space(1))) unsigned int*)g,
        (__attribute__((address_space(3))) unsigned int*)l, 16, 0, 0);
}

// ---------------------------------------------------------------------------
// bf16 MFMA GEMM: tile 128x128, BK=64, 8 waves, counted-vmcnt double buffer,
// XOR-chunk swizzle (chunk c of row r at slot c^(r&7); both-sides rule).
// T1 XCD swizzle: 1D launch; physical block id p on XCD (p&7) is remapped to
// logical lin = (p&7)*(nwg/8) + (p>>3)  -> each XCD gets a CONTIGUOUS range
// of logical blocks, so the blocks sharing A/B panels co-reside on one XCD's
// L2 (panel fetched once per XCD, not 4-8x). Bijective since nwg%8==0.
// Wave w (wr=w>>2, wc=w&3) owns a 64x32 output sub-tile: acc[4][2].
// STATS: also emit per-block (sum, sumsq) fp32 partials for InstanceNorm.
// ---------------------------------------------------------------------------
template<typename OutT, bool STATS>
__global__ __launch_bounds__(512, 4)
void gemm_bt(const unsigned short* __restrict__ A, const unsigned short* __restrict__ B,
             OutT* __restrict__ C, float2* __restrict__ sp_out,
             int nx, int ny,
             int K, long lda, long ldb, long ldc,
             long sa_bb, long sa_bh, long sb_bb, long sb_bh, long sc_z,
             int H, float alpha)
{
    __shared__ unsigned short As[2][128 * 64];
    __shared__ unsigned short Bs[2][128 * 64];

    // T1: XCD-contiguous logical block id
    const int nwg = (int)gridDim.x;
    const int cpx = nwg >> 3;
    const int phys = (int)blockIdx.x;
    const int lin = (phys & 7) * cpx + (phys >> 3);
    const int z   = lin / (nx * ny);
    const int rem = lin - z * (nx * ny);
    const int by  = rem / nx;
    const int bx  = rem - by * nx;

    const int bb = z / H, hh = z - bb * H;
    A += (long)bb * sa_bb + (long)hh * sa_bh;
    B += (long)bb * sb_bb + (long)hh * sb_bh;
    C += (long)z * sc_z;

    const int tid  = threadIdx.x;
    const int lane = tid & 63;
    const int wave = tid >> 6;           // 0..7
    const int wr = wave >> 2, wc = wave & 3;

    const long m0 = (long)by * 128;
    const long n0 = (long)bx * 128;

    // staging: wave stages 16 rows x 64 k per operand as two 8-row chunks.
    const int lrow = lane >> 3;                            // 0..7
    const int kc   = ((lane & 7) ^ (lrow & 7)) * 8;        // swizzled k elem
    const unsigned short* ga0 = A + (m0 + wave * 16 + lrow) * lda + kc;
    const unsigned short* ga1 = ga0 + 8 * lda;
    const unsigned short* gb0 = B + (n0 + wave * 16 + lrow) * ldb + kc;
    const unsigned short* gb1 = gb0 + 8 * ldb;

    auto stg = [&](int buf, long koff) {
        gl2lds16(ga0 + koff, &As[buf][wave * 1024]);
        gl2lds16(ga1 + koff, &As[buf][wave * 1024 + 512]);
        gl2lds16(gb0 + koff, &Bs[buf][wave * 1024]);
        gl2lds16(gb1 + koff, &Bs[buf][wave * 1024 + 512]);
    };

    const int fr = lane & 15;
    const int hi = lane >> 4;            // 0..3
    const int sw = fr & 7;               // read-side swizzle key

    f32x4 acc[4][2];
    const f32x4 zero4 = {0.f, 0.f, 0.f, 0.f};
    #pragma unroll
    for (int i = 0; i < 4; ++i)
        #pragma unroll
        for (int j = 0; j < 2; ++j) acc[i][j] = zero4;

    // prologue: two stages in flight (8 loads/wave)
    stg(0, 0);
    stg(1, 64);

    int cur = 0;
    for (long k0 = 0; k0 < K; k0 += 64) {
        if (k0 + 64 < K) {
            asm volatile("s_waitcnt vmcnt(4)" ::: "memory");
        } else {
            asm volatile("s_waitcnt vmcnt(0)" ::: "memory");
        }
        __builtin_amdgcn_s_barrier();    // buf[cur] landed for all waves

        #pragma unroll
        for (int kk = 0; kk < 2; ++kk) {
            short8 af[4], bfr[2];
            #pragma unroll
            for (int i = 0; i < 4; ++i) {
                const int row = wr * 64 + i * 16 + fr;
                af[i] = *(const short8*)(&As[cur][row * 64 + (((kk * 4 + hi) ^ sw) * 8)]);
            }
            #pragma unroll
            for (int j = 0; j < 2; ++j) {
                const int row = wc * 32 + j * 16 + fr;
                bfr[j] = *(const short8*)(&Bs[cur][row * 64 + (((kk * 4 + hi) ^ sw) * 8)]);
            }
            #pragma unroll
            for (int i = 0; i < 4; ++i)
                #pragma unroll
                for (int j = 0; j < 2; ++j)
                    acc[i][j] = __builtin_amdgcn_mfma_f32_16x16x32_bf16(af[i], bfr[j], acc[i][j], 0, 0, 0);
        }

        asm volatile("s_waitcnt lgkmcnt(0)" ::: "memory");
        __builtin_amdgcn_s_barrier();    // all waves done reading buf[cur]
        if (k0 + 128 < K) stg(cur, k0 + 128);
        cur ^= 1;
    }

    float s = 0.f, s2 = 0.f;
    const int orow = hi * 4;
    #pragma unroll
    for (int i = 0; i < 4; ++i) {
        const long rbase = m0 + wr * 64 + i * 16 + orow;
        #pragma unroll
        for (int j = 0; j < 2; ++j) {
            const long cidx = n0 + wc * 32 + j * 16 + fr;
            f32x4 v = acc[i][j];
            #pragma unroll
            for (int q = 0; q < 4; ++q) {
                float val = alpha * v[q];
                if constexpr (STATS) { s += val; s2 += val * val; }
                if constexpr (sizeof(OutT) == 4) C[(rbase + q) * ldc + cidx] = val;
                else                             C[(rbase + q) * ldc + cidx] = f2bf(val);
            }
        }
    }

    if constexpr (STATS) {
        float* red = (float*)&As[0][0];
        red[tid] = s; red[512 + tid] = s2;
        __syncthreads();
        for (int off = 256; off > 0; off >>= 1) {
            if (tid < off) { red[tid] += red[tid + off]; red[512 + tid] += red[512 + tid + off]; }
            __syncthreads();
        }
        if (tid == 0)
            sp_out[(long)z * 32 + by * nx + bx] = make_float2(red[0], red[512]);
    }
}

// ---------------------------------------------------------------------------
// 64x64 transpose-cast worker, LDS-vectorized; outT row pitch = ldaT.
// ---------------------------------------------------------------------------
__device__ __forceinline__
void tc64_impl(const float* __restrict__ in, unsigned short* __restrict__ outT,
               unsigned short* __restrict__ outB, int R, int Cin, long ldaT,
               int bx, int by, bool dual, unsigned short (*t)[68])
{
    const int r0 = bx * 64, c0 = by * 64;
    const int tid = threadIdx.x;
    const int rr  = tid >> 4;          // 0..15
    const int cc4 = (tid & 15) * 4;    // 0..60
    const bool real = (c0 + cc4) < Cin;

    #pragma unroll
    for (int i = 0; i < 4; ++i) {
        const int r = rr + i * 16;
        float4 v = make_float4(0.f, 0.f, 0.f, 0.f);
        if (real) v = *(const float4*)(in + (long)(r0 + r) * Cin + c0 + cc4);
        ushort4 o;
        o.x = f2bf(v.x); o.y = f2bf(v.y); o.z = f2bf(v.z); o.w = f2bf(v.w);
        *(ushort4*)&t[r][cc4] = o;
        if (dual && real)
            *(ushort4*)(outB + (long)(r0 + r) * Cin + c0 + cc4) = o;
    }
    __syncthreads();
    #pragma unroll
    for (int i = 0; i < 2; ++i) {
        const int p = rr + i * 16;      // 0..31 -> out-row pair (2p, 2p+1)
        const int c = 2 * p;
        ushort2 a0 = *(const ushort2*)&t[cc4 + 0][c];
        ushort2 a1 = *(const ushort2*)&t[cc4 + 1][c];
        ushort2 a2 = *(const ushort2*)&t[cc4 + 2][c];
        ushort2 a3 = *(const ushort2*)&t[cc4 + 3][c];
        ushort4 w0; w0.x = a0.x; w0.y = a1.x; w0.z = a2.x; w0.w = a3.x;
        ushort4 w1; w1.x = a0.y; w1.y = a1.y; w1.z = a2.y; w1.w = a3.y;
        *(ushort4*)(outT + (long)(c0 + c) * ldaT + r0 + cc4)     = w0;
        *(ushort4*)(outT + (long)(c0 + c + 1) * ldaT + r0 + cc4) = w1;
    }
}

// ---------------------------------------------------------------------------
// ALL preps in one launch (block-range segmented).
// ---------------------------------------------------------------------------
__global__ __launch_bounds__(256)
void prep_all(const float* __restrict__ emb, const float* __restrict__ emb_all,
              const float* __restrict__ Wq, const float* __restrict__ Wk,
              const float* __restrict__ Wv, const float* __restrict__ Wo,
              unsigned short* __restrict__ embT, unsigned short* __restrict__ emb_allT,
              unsigned short* __restrict__ emb_allB, unsigned short* __restrict__ WqB,
              unsigned short* __restrict__ WkB, unsigned short* __restrict__ WvT,
              unsigned short* __restrict__ WoB)
{
    __shared__ unsigned short t[64][68];
    int bid = blockIdx.x;
    if (bid < 4096) {
        const int z = bid >> 10, r2 = bid & 1023, by = r2 >> 6, bx = r2 & 63;
        tc64_impl(emb_all + (long)z * 4096 * 960, emb_allT + (long)z * 1024 * 4096,
                  emb_allB + (long)z * 4096 * 960, 4096, 960, 4096, bx, by, true, t);
        return;
    }
    bid -= 4096;
    if (bid < 2048) {
        const int z = bid >> 9, r2 = bid & 511, by = r2 >> 6, bx = r2 & 63;
        tc64_impl(emb + (long)z * 4096 * 512, embT + (long)z * 512 * 4096,
                  nullptr, 4096, 512, 4096, bx, by, false, t);
        return;
    }
    bid -= 2048;
    if (bid < 960) {
        const int z = bid / 240, r2 = bid % 240, by = r2 / 15, bx = r2 % 15;
        tc64_impl(Wv + (long)z * 960 * 960, WvT + (long)z * 1024 * 960,
                  nullptr, 960, 960, 960, bx, by, false, t);
        return;
    }
    bid -= 960;
    long q = (long)bid * 256 + threadIdx.x;
    if (q < 983040) {                       // WkB
        long e = q * 4;
        long h = e / 983040L; long r2 = e - h * 983040L;
        long r = r2 / 960;    long c = r2 - r * 960;
        ushort4 o = {0, 0, 0, 0};
        if (r < 960) {
            float4 v = *(const float4*)(Wk + (h * 960 + r) * 960 + c);
            o.x = f2bf(v.x); o.y = f2bf(v.y); o.z = f2bf(v.z); o.w = f2bf(v.w);
        }
        *(ushort4*)(WkB + e) = o;
        return;
    }
    q -= 983040;
    if (q < 262144) {                       // WqB
        long e = q * 4;
        float4 v = *(const float4*)(Wq + e);
        ushort4 o; o.x = f2bf(v.x); o.y = f2bf(v.y); o.z = f2bf(v.z); o.w = f2bf(v.w);
        *(ushort4*)(WqB + e) = o;
        return;
    }
    q -= 262144;
    if (q < 65536) {                        // WoB
        long e = q * 4;
        float4 v = *(const float4*)(Wo + e);
        ushort4 o; o.x = f2bf(v.x); o.y = f2bf(v.y); o.z = f2bf(v.z); o.w = f2bf(v.w);
        *(ushort4*)(WoB + e) = o;
    }
}

// GT[b][r] = f2bf(sum_sp bf16 partK[b][sp][r]); 8 elems/thread, 1024 blocks.
__global__ __launch_bounds__(256)
void reduce_gt(const unsigned short* __restrict__ part, unsigned short* __restrict__ GT)
{
    long i = ((long)blockIdx.x * 256 + threadIdx.x) * 8;
    long b = i >> 19, r = i & 524287;
    const unsigned short* p = part + b * 4 * 524288 + r;
    const short8 v0 = *(const short8*)(p);
    const short8 v1 = *(const short8*)(p + 524288);
    const short8 v2 = *(const short8*)(p + 2 * 524288);
    const short8 v3 = *(const short8*)(p + 3 * 524288);
    short8 o;
    #pragma unroll
    for (int k = 0; k < 8; ++k) {
        float s = bf2f((unsigned short)v0[k]) + bf2f((unsigned short)v1[k])
                + bf2f((unsigned short)v2[k]) + bf2f((unsigned short)v3[k]);
        o[k] = (short)f2bf(s);
    }
    *(short8*)(GT + i) = o;
}

// ---------------------------------------------------------------------------
// norm + softmax, one WAVE per row (shfl-only reductions).
// ---------------------------------------------------------------------------
__global__ __launch_bounds__(256)
void norm_softmax(const unsigned short* __restrict__ SC, const float2* __restrict__ part,
                  unsigned short* __restrict__ probs)
{
    const int lane = threadIdx.x & 63;
    const int wave = threadIdx.x >> 6;
    const long row = (long)blockIdx.x * 4 + wave;
    const int z = (int)(row >> 9);

    float2 pv = part[z * 32 + (lane & 31)];
    float a = pv.x, b = pv.y;
    #pragma unroll
    for (int off = 1; off < 32; off <<= 1) {
        a += __shfl_xor(a, off);
        b += __shfl_xor(b, off);
    }
    const float ninv = 1.f / (512.f * 960.f);
    const float mean = a * ninv;
    const float rstd = rsqrtf(b * ninv - mean * mean + 960.f * 1e-5f);

    const unsigned short* p = SC + row * 1024 + lane * 16;
    const bool act = lane < 60;
    float x[16];
    {
        const short8 w0 = *(const short8*)(p);
        const short8 w1 = *(const short8*)(p + 8);
        #pragma unroll
        for (int k = 0; k < 8; ++k) {
            x[k]     = (bf2f((unsigned short)w0[k]) - mean) * rstd;
            x[k + 8] = (bf2f((unsigned short)w1[k]) - mean) * rstd;
        }
    }
    float mx = -1e30f;
    if (act) {
        #pragma unroll
        for (int k = 0; k < 16; ++k) mx = fmaxf(mx, x[k]);
    }
    #pragma unroll
    for (int off = 1; off < 64; off <<= 1) mx = fmaxf(mx, __shfl_xor(mx, off));

    float s = 0.f;
    if (act) {
        #pragma unroll
        for (int k = 0; k < 16; ++k) { x[k] = __expf(x[k] - mx); s += x[k]; }
    }
    #pragma unroll
    for (int off = 1; off < 64; off <<= 1) s += __shfl_xor(s, off);
    const float inv = 1.f / s;

    unsigned short* o = probs + row * 1024 + lane * 16;
    short8 o0 = {0,0,0,0,0,0,0,0}, o1 = {0,0,0,0,0,0,0,0};
    if (act) {
        #pragma unroll
        for (int k = 0; k < 8; ++k) {
            o0[k] = (short)f2bf(x[k] * inv);
            o1[k] = (short)f2bf(x[k + 8] * inv);
        }
    }
    *(short8*)(o)     = o0;
    *(short8*)(o + 8) = o1;
}

// ---------------------------------------------------------------------------
// UbarT[b] = sum_h UT[b*4+h]; 8 elems/thread.
// ---------------------------------------------------------------------------
__global__ __launch_bounds__(256)
void mean_heads(const unsigned short* __restrict__ UT, unsigned short* __restrict__ Ub)
{
    const long per = 1024L * 512;
    long e = ((long)blockIdx.x * 256 + threadIdx.x) * 8;
    long b = e / per; long r = e - b * per;
    const short8 v0 = *(const short8*)(UT + (b * 4 + 0) * per + r);
    const short8 v1 = *(const short8*)(UT + (b * 4 + 1) * per + r);
    const short8 v2 = *(const short8*)(UT + (b * 4 + 2) * per + r);
    const short8 v3 = *(const short8*)(UT + (b * 4 + 3) * per + r);
    short8 o;
    #pragma unroll
    for (int k = 0; k < 8; ++k) {
        float s = bf2f((unsigned short)v0[k]) + bf2f((unsigned short)v1[k])
                + bf2f((unsigned short)v2[k]) + bf2f((unsigned short)v3[k]);
        o[k] = (short)f2bf(s);
    }
    *(short8*)(Ub + b * per + r) = o;
}

// ---------------------------------------------------------------------------
extern "C" void kernel_launch(void* const* d_in, const int* in_sizes, int n_in,
                              void* d_out, int out_size, void* d_ws, size_t ws_size,
                              hipStream_t stream)
{
    const float* emb     = (const float*)d_in[0];  // [4][4096][512]
    const float* emb_all = (const float*)d_in[1];  // [4][4096][960]
    const float* Wq      = (const float*)d_in[2];  // [4][512][512]
    const float* Wk      = (const float*)d_in[3];  // [4][960][960]
    const float* Wv      = (const float*)d_in[4];  // [4][960][960]
    const float* Wo      = (const float*)d_in[5];  // [512][512]
    float* out = (float*)d_out;

    char* ws = (char*)d_ws;
    unsigned short* embT     = (unsigned short*)(ws);              // [b][512][4096]
    unsigned short* emb_allT = (unsigned short*)(ws + 16777216);   // [b][1024][4096]
    unsigned short* emb_allB = (unsigned short*)(ws + 50331648);   // [b][4096][960]
    unsigned short* WqB      = (unsigned short*)(ws + 81788928);   // [h][512][512]
    unsigned short* WkB      = (unsigned short*)(ws + 83886080);   // [h][1024][960]
    unsigned short* WvT      = (unsigned short*)(ws + 91750400);   // [h][1024][960]
    unsigned short* WoB      = (unsigned short*)(ws + 99614720);   // [512][512]
    unsigned short* GT       = (unsigned short*)(ws + 100139008);  // [b][1024][512]
    unsigned short* probs    = (unsigned short*)(ws + 104333312);  // [z][512][1024]
    float2* sc_part          = (float2*)(ws + 121110528);          // [16][32]
    unsigned short* partK    = (unsigned short*)(ws + 134217728);  // 16 MB bf16

    // region reuse (sequential liveness)
    unsigned short* S1  = embT;                             // embT dead after splitk
    unsigned short* SC  = emb_allT;                         // emb_allT dead after splitk
    unsigned short* UT  = (unsigned short*)(ws + 33554432); // 2nd half of emb_allT region
    unsigned short* UbT = GT;                               // GT dead after step 2
    unsigned short* W2  = embT;                             // S1 dead after step 3

    // ---- 0. all preps, one launch ----
    prep_all<<<12224, 256, 0, stream>>>(emb, emb_all, Wq, Wk, Wv, Wo,
                                        embT, emb_allT, emb_allB, WqB, WkB, WvT, WoB);

    // ---- 1. split-K (z = b*4+sp): partK[z] = emb_allT chunk x embT chunk^T ----
    gemm_bt<unsigned short, false><<<512, 512, 0, stream>>>(
        emb_allT, embT, partK, nullptr, 4, 8, 1024, 4096, 4096, 512,
        1024L*4096, 1024, 512L*4096, 1024, 1024L*512, 4, 1.f);
    reduce_gt<<<1024, 256, 0, stream>>>(partK, GT);

    // ---- 2. S1[b,h] = Wq[h] x GT[b]^T  (M=512, N=1024, K=512) ----
    gemm_bt<unsigned short, false><<<512, 512, 0, stream>>>(
        WqB, GT, S1, nullptr, 8, 4, 512, 512, 512, 1024,
        0, 512L*512, 1024L*512, 0, 512L*1024, 4, 1.f);

    // ---- 3. SC[z] = S1[z] x WkB[h]^T (bf16 out) + fused stats partials ----
    gemm_bt<unsigned short, true><<<512, 512, 0, stream>>>(
        S1, WkB, SC, sc_part, 8, 4, 960, 1024, 960, 1024,
        4L*512*1024, 512L*1024, 0, 1024L*960, 512L*1024, 4, 1.f);

    // ---- 4. fused instance-norm + softmax (wave-per-row) ----
    norm_softmax<<<2048, 256, 0, stream>>>(SC, sc_part, probs);

    // ---- 5. UT[z] = WvT[h] x probs[z]^T * 0.25  (M=1024, N=512, K=960) ----
    gemm_bt<unsigned short, false><<<512, 512, 0, stream>>>(
        WvT, probs, UT, nullptr, 4, 8, 960, 960, 1024, 512,
        0, 1024L*960, 4L*512*1024, 512L*1024, 1024L*512, 4, 0.25f);

    // ---- 6. UbT[b] = sum_h UT[b,h] ----
    mean_heads<<<1024, 256, 0, stream>>>(UT, UbT);

    // ---- 7. W2[b] = WoB x UbT[b]^T  (M=512, N=1024, K=512) ----
    gemm_bt<unsigned short, false><<<128, 512, 0, stream>>>(
        WoB, UbT, W2, nullptr, 8, 4, 512, 512, 512, 1024,
        0, 0, 1024L*512, 0, 512L*1024, 1, 1.f);

    // ---- 8. out[b] = emb_allB[b] x W2[b]^T  (M=4096, N=512, K=960) ----
    gemm_bt<float, false><<<512, 512, 0, stream>>>(
        emb_allB, W2, out, nullptr, 4, 32, 960, 960, 1024, 512,
        4096L*960, 0, 512L*1024, 0, 4096L*512, 1, 1.f);
}

// Round 16
// 172.847 us; speedup vs baseline: 1.1338x; 1.0002x over previous
//
#include <hip/hip_runtime.h>
#include <math.h>

typedef __attribute__((ext_vector_type(8))) short short8;
typedef __attribute__((ext_vector_type(4))) float f32x4;

__device__ __forceinline__ unsigned short f2bf(float f) {
    unsigned int u; __builtin_memcpy(&u, &f, 4);
    unsigned int r = (u + 0x7FFFu + ((u >> 16) & 1u)) >> 16;
    return (unsigned short)r;
}
__device__ __forceinline__ float bf2f(unsigned short h) {
    unsigned int u = ((unsigned int)h) << 16;
    float f; __builtin_memcpy(&f, &u, 4); return f;
}
__device__ __forceinline__ void gl2lds16(const unsigned short* g, unsigned short* l) {
    __builtin_amdgcn_global_load_lds(
        (const __attribute__((address_space(1))) unsigned int*)g,
        (__attribute__((address_space(3))) unsigned int*)l, 16, 0, 0);
}

// ---------------------------------------------------------------------------
// bf16 MFMA GEMM: tile 128x128, BK=64, 8 waves, counted-vmcnt double buffer,
// XOR-chunk swizzle (chunk c of row r at slot c^(r&7); both-sides rule),
// T1 XCD-contiguous block remap (1D launch, nwg%8==0, bijective).
// TILED: A/B are in 64x64-tile-blocked layout (tile (row>>6)*(K/64)+(k>>6)
//   stored contiguously as 4096 elems); lda/ldb = row-tile stride (64*4096);
//   per-K-step advance = +4096 elems. Lets the producer (prep transpose)
//   write dense 8KB tiles (DRAM page locality) instead of 8KB-strided rows.
// Wave w (wr=w>>2, wc=w&3) owns a 64x32 output sub-tile: acc[4][2].
// STATS: also emit per-block (sum, sumsq) fp32 partials for InstanceNorm.
// ---------------------------------------------------------------------------
template<typename OutT, bool STATS, bool TILED>
__global__ __launch_bounds__(512, 4)
void gemm_bt(const unsigned short* __restrict__ A, const unsigned short* __restrict__ B,
             OutT* __restrict__ C, float2* __restrict__ sp_out,
             int nx, int ny,
             int K, long lda, long ldb, long ldc,
             long sa_bb, long sa_bh, long sb_bb, long sb_bh, long sc_z,
             int H, float alpha)
{
    __shared__ unsigned short As[2][128 * 64];
    __shared__ unsigned short Bs[2][128 * 64];

    // T1: XCD-contiguous logical block id
    const int nwg = (int)gridDim.x;
    const int cpx = nwg >> 3;
    const int phys = (int)blockIdx.x;
    const int lin = (phys & 7) * cpx + (phys >> 3);
    const int z   = lin / (nx * ny);
    const int rem = lin - z * (nx * ny);
    const int by  = rem / nx;
    const int bx  = rem - by * nx;

    const int bb = z / H, hh = z - bb * H;
    A += (long)bb * sa_bb + (long)hh * sa_bh;
    B += (long)bb * sb_bb + (long)hh * sb_bh;
    C += (long)z * sc_z;

    const int tid  = threadIdx.x;
    const int lane = tid & 63;
    const int wave = tid >> 6;           // 0..7
    const int wr = wave >> 2, wc = wave & 3;

    const long m0 = (long)by * 128;
    const long n0 = (long)bx * 128;

    // staging: wave stages 16 rows x 64 k per operand as two 8-row chunks.
    const int lrow = lane >> 3;                            // 0..7
    const int kc   = ((lane & 7) ^ (lrow & 7)) * 8;        // swizzled k elem
    const unsigned short *ga0, *ga1, *gb0, *gb1;
    if constexpr (TILED) {
        const long am = m0 + wave * 16 + lrow;   // in-tile m offset <= 55, +8 stays in tile
        ga0 = A + (am >> 6) * lda + (am & 63) * 64 + kc;
        ga1 = ga0 + 8 * 64;
        const long bn = n0 + wave * 16 + lrow;
        gb0 = B + (bn >> 6) * ldb + (bn & 63) * 64 + kc;
        gb1 = gb0 + 8 * 64;
    } else {
        ga0 = A + (m0 + wave * 16 + lrow) * lda + kc;
        ga1 = ga0 + 8 * lda;
        gb0 = B + (n0 + wave * 16 + lrow) * ldb + kc;
        gb1 = gb0 + 8 * ldb;
    }

    auto stg = [&](int buf, long koff) {
        const long off = TILED ? (koff >> 6) * 4096 : koff;
        gl2lds16(ga0 + off, &As[buf][wave * 1024]);
        gl2lds16(ga1 + off, &As[buf][wave * 1024 + 512]);
        gl2lds16(gb0 + off, &Bs[buf][wave * 1024]);
        gl2lds16(gb1 + off, &Bs[buf][wave * 1024 + 512]);
    };

    const int fr = lane & 15;
    const int hi = lane >> 4;            // 0..3
    const int sw = fr & 7;               // read-side swizzle key

    f32x4 acc[4][2];
    const f32x4 zero4 = {0.f, 0.f, 0.f, 0.f};
    #pragma unroll
    for (int i = 0; i < 4; ++i)
        #pragma unroll
        for (int j = 0; j < 2; ++j) acc[i][j] = zero4;

    // prologue: two stages in flight (8 loads/wave)
    stg(0, 0);
    stg(1, 64);

    int cur = 0;
    for (long k0 = 0; k0 < K; k0 += 64) {
        if (k0 + 64 < K) {
            asm volatile("s_waitcnt vmcnt(4)" ::: "memory");
        } else {
            asm volatile("s_waitcnt vmcnt(0)" ::: "memory");
        }
        __builtin_amdgcn_s_barrier();    // buf[cur] landed for all waves

        #pragma unroll
        for (int kk = 0; kk < 2; ++kk) {
            short8 af[4], bfr[2];
            #pragma unroll
            for (int i = 0; i < 4; ++i) {
                const int row = wr * 64 + i * 16 + fr;
                af[i] = *(const short8*)(&As[cur][row * 64 + (((kk * 4 + hi) ^ sw) * 8)]);
            }
            #pragma unroll
            for (int j = 0; j < 2; ++j) {
                const int row = wc * 32 + j * 16 + fr;
                bfr[j] = *(const short8*)(&Bs[cur][row * 64 + (((kk * 4 + hi) ^ sw) * 8)]);
            }
            #pragma unroll
            for (int i = 0; i < 4; ++i)
                #pragma unroll
                for (int j = 0; j < 2; ++j)
                    acc[i][j] = __builtin_amdgcn_mfma_f32_16x16x32_bf16(af[i], bfr[j], acc[i][j], 0, 0, 0);
        }

        asm volatile("s_waitcnt lgkmcnt(0)" ::: "memory");
        __builtin_amdgcn_s_barrier();    // all waves done reading buf[cur]
        if (k0 + 128 < K) stg(cur, k0 + 128);
        cur ^= 1;
    }

    float s = 0.f, s2 = 0.f;
    const int orow = hi * 4;
    #pragma unroll
    for (int i = 0; i < 4; ++i) {
        const long rbase = m0 + wr * 64 + i * 16 + orow;
        #pragma unroll
        for (int j = 0; j < 2; ++j) {
            const long cidx = n0 + wc * 32 + j * 16 + fr;
            f32x4 v = acc[i][j];
            #pragma unroll
            for (int q = 0; q < 4; ++q) {
                float val = alpha * v[q];
                if constexpr (STATS) { s += val; s2 += val * val; }
                if constexpr (sizeof(OutT) == 4) C[(rbase + q) * ldc + cidx] = val;
                else                             C[(rbase + q) * ldc + cidx] = f2bf(val);
            }
        }
    }

    if constexpr (STATS) {
        float* red = (float*)&As[0][0];
        red[tid] = s; red[512 + tid] = s2;
        __syncthreads();
        for (int off = 256; off > 0; off >>= 1) {
            if (tid < off) { red[tid] += red[tid + off]; red[512 + tid] += red[512 + tid + off]; }
            __syncthreads();
        }
        if (tid == 0)
            sp_out[(long)z * 32 + by * nx + bx] = make_float2(red[0], red[512]);
    }
}

// ---------------------------------------------------------------------------
// 64x64 transpose-cast worker, LDS-vectorized.
// tiledT: outT is 64x64-tile-blocked — this block's transposed tile is ONE
//   dense 8KB region (tile index by*(R/64)+bx), giving the write stream DRAM
//   page locality. Otherwise row pitch = ldaT.
// ---------------------------------------------------------------------------
__device__ __forceinline__
void tc64_impl(const float* __restrict__ in, unsigned short* __restrict__ outT,
               unsigned short* __restrict__ outB, int R, int Cin, long ldaT,
               int bx, int by, bool dual, bool tiledT, unsigned short (*t)[68])
{
    const int r0 = bx * 64, c0 = by * 64;
    const int tid = threadIdx.x;
    const int rr  = tid >> 4;          // 0..15
    const int cc4 = (tid & 15) * 4;    // 0..60
    const bool real = (c0 + cc4) < Cin;

    #pragma unroll
    for (int i = 0; i < 4; ++i) {
        const int r = rr + i * 16;
        float4 v = make_float4(0.f, 0.f, 0.f, 0.f);
        if (real) v = *(const float4*)(in + (long)(r0 + r) * Cin + c0 + cc4);
        ushort4 o;
        o.x = f2bf(v.x); o.y = f2bf(v.y); o.z = f2bf(v.z); o.w = f2bf(v.w);
        *(ushort4*)&t[r][cc4] = o;
        if (dual && real)
            *(ushort4*)(outB + (long)(r0 + r) * Cin + c0 + cc4) = o;
    }
    __syncthreads();
    unsigned short* tb = outT + ((long)by * (R >> 6) + bx) * 4096;
    #pragma unroll
    for (int i = 0; i < 2; ++i) {
        const int p = rr + i * 16;      // 0..31 -> out-row pair (2p, 2p+1)
        const int c = 2 * p;
        ushort2 a0 = *(const ushort2*)&t[cc4 + 0][c];
        ushort2 a1 = *(const ushort2*)&t[cc4 + 1][c];
        ushort2 a2 = *(const ushort2*)&t[cc4 + 2][c];
        ushort2 a3 = *(const ushort2*)&t[cc4 + 3][c];
        ushort4 w0; w0.x = a0.x; w0.y = a1.x; w0.z = a2.x; w0.w = a3.x;
        ushort4 w1; w1.x = a0.y; w1.y = a1.y; w1.z = a2.y; w1.w = a3.y;
        if (tiledT) {
            *(ushort4*)(tb + c * 64 + cc4)       = w0;
            *(ushort4*)(tb + (c + 1) * 64 + cc4) = w1;
        } else {
            *(ushort4*)(outT + (long)(c0 + c) * ldaT + r0 + cc4)     = w0;
            *(ushort4*)(outT + (long)(c0 + c + 1) * ldaT + r0 + cc4) = w1;
        }
    }
}

// ---------------------------------------------------------------------------
// ALL preps in one launch (block-range segmented).
// emb_allT and embT are written TILE-BLOCKED (consumed only by splitk).
// ---------------------------------------------------------------------------
__global__ __launch_bounds__(256)
void prep_all(const float* __restrict__ emb, const float* __restrict__ emb_all,
              const float* __restrict__ Wq, const float* __restrict__ Wk,
              const float* __restrict__ Wv, const float* __restrict__ Wo,
              unsigned short* __restrict__ embT, unsigned short* __restrict__ emb_allT,
              unsigned short* __restrict__ emb_allB, unsigned short* __restrict__ WqB,
              unsigned short* __restrict__ WkB, unsigned short* __restrict__ WvT,
              unsigned short* __restrict__ WoB)
{
    __shared__ unsigned short t[64][68];
    int bid = blockIdx.x;
    if (bid < 4096) {
        const int z = bid >> 10, r2 = bid & 1023, by = r2 >> 6, bx = r2 & 63;
        tc64_impl(emb_all + (long)z * 4096 * 960, emb_allT + (long)z * 1024 * 4096,
                  emb_allB + (long)z * 4096 * 960, 4096, 960, 4096, bx, by, true, true, t);
        return;
    }
    bid -= 4096;
    if (bid < 2048) {
        const int z = bid >> 9, r2 = bid & 511, by = r2 >> 6, bx = r2 & 63;
        tc64_impl(emb + (long)z * 4096 * 512, embT + (long)z * 512 * 4096,
                  nullptr, 4096, 512, 4096, bx, by, false, true, t);
        return;
    }
    bid -= 2048;
    if (bid < 960) {
        const int z = bid / 240, r2 = bid % 240, by = r2 / 15, bx = r2 % 15;
        tc64_impl(Wv + (long)z * 960 * 960, WvT + (long)z * 1024 * 960,
                  nullptr, 960, 960, 960, bx, by, false, false, t);
        return;
    }
    bid -= 960;
    long q = (long)bid * 256 + threadIdx.x;
    if (q < 983040) {                       // WkB
        long e = q * 4;
        long h = e / 983040L; long r2 = e - h * 983040L;
        long r = r2 / 960;    long c = r2 - r * 960;
        ushort4 o = {0, 0, 0, 0};
        if (r < 960) {
            float4 v = *(const float4*)(Wk + (h * 960 + r) * 960 + c);
            o.x = f2bf(v.x); o.y = f2bf(v.y); o.z = f2bf(v.z); o.w = f2bf(v.w);
        }
        *(ushort4*)(WkB + e) = o;
        return;
    }
    q -= 983040;
    if (q < 262144) {                       // WqB
        long e = q * 4;
        float4 v = *(const float4*)(Wq + e);
        ushort4 o; o.x = f2bf(v.x); o.y = f2bf(v.y); o.z = f2bf(v.z); o.w = f2bf(v.w);
        *(ushort4*)(WqB + e) = o;
        return;
    }
    q -= 262144;
    if (q < 65536) {                        // WoB
        long e = q * 4;
        float4 v = *(const float4*)(Wo + e);
        ushort4 o; o.x = f2bf(v.x); o.y = f2bf(v.y); o.z = f2bf(v.z); o.w = f2bf(v.w);
        *(ushort4*)(WoB + e) = o;
    }
}

// GT[b][r] = f2bf(sum_sp bf16 partK[b][sp][r]); 8 elems/thread, 1024 blocks.
__global__ __launch_bounds__(256)
void reduce_gt(const unsigned short* __restrict__ part, unsigned short* __restrict__ GT)
{
    long i = ((long)blockIdx.x * 256 + threadIdx.x) * 8;
    long b = i >> 19, r = i & 524287;
    const unsigned short* p = part + b * 4 * 524288 + r;
    const short8 v0 = *(const short8*)(p);
    const short8 v1 = *(const short8*)(p + 524288);
    const short8 v2 = *(const short8*)(p + 2 * 524288);
    const short8 v3 = *(const short8*)(p + 3 * 524288);
    short8 o;
    #pragma unroll
    for (int k = 0; k < 8; ++k) {
        float s = bf2f((unsigned short)v0[k]) + bf2f((unsigned short)v1[k])
                + bf2f((unsigned short)v2[k]) + bf2f((unsigned short)v3[k]);
        o[k] = (short)f2bf(s);
    }
    *(short8*)(GT + i) = o;
}

// ---------------------------------------------------------------------------
// norm + softmax, one WAVE per row (shfl-only reductions).
// ---------------------------------------------------------------------------
__global__ __launch_bounds__(256)
void norm_softmax(const unsigned short* __restrict__ SC, const float2* __restrict__ part,
                  unsigned short* __restrict__ probs)
{
    const int lane = threadIdx.x & 63;
    const int wave = threadIdx.x >> 6;
    const long row = (long)blockIdx.x * 4 + wave;
    const int z = (int)(row >> 9);

    float2 pv = part[z * 32 + (lane & 31)];
    float a = pv.x, b = pv.y;
    #pragma unroll
    for (int off = 1; off < 32; off <<= 1) {
        a += __shfl_xor(a, off);
        b += __shfl_xor(b, off);
    }
    const float ninv = 1.f / (512.f * 960.f);
    const float mean = a * ninv;
    const float rstd = rsqrtf(b * ninv - mean * mean + 960.f * 1e-5f);

    const unsigned short* p = SC + row * 1024 + lane * 16;
    const bool act = lane < 60;
    float x[16];
    {
        const short8 w0 = *(const short8*)(p);
        const short8 w1 = *(const short8*)(p + 8);
        #pragma unroll
        for (int k = 0; k < 8; ++k) {
            x[k]     = (bf2f((unsigned short)w0[k]) - mean) * rstd;
            x[k + 8] = (bf2f((unsigned short)w1[k]) - mean) * rstd;
        }
    }
    float mx = -1e30f;
    if (act) {
        #pragma unroll
        for (int k = 0; k < 16; ++k) mx = fmaxf(mx, x[k]);
    }
    #pragma unroll
    for (int off = 1; off < 64; off <<= 1) mx = fmaxf(mx, __shfl_xor(mx, off));

    float s = 0.f;
    if (act) {
        #pragma unroll
        for (int k = 0; k < 16; ++k) { x[k] = __expf(x[k] - mx); s += x[k]; }
    }
    #pragma unroll
    for (int off = 1; off < 64; off <<= 1) s += __shfl_xor(s, off);
    const float inv = 1.f / s;

    unsigned short* o = probs + row * 1024 + lane * 16;
    short8 o0 = {0,0,0,0,0,0,0,0}, o1 = {0,0,0,0,0,0,0,0};
    if (act) {
        #pragma unroll
        for (int k = 0; k < 8; ++k) {
            o0[k] = (short)f2bf(x[k] * inv);
            o1[k] = (short)f2bf(x[k + 8] * inv);
        }
    }
    *(short8*)(o)     = o0;
    *(short8*)(o + 8) = o1;
}

// ---------------------------------------------------------------------------
// UbarT[b] = sum_h UT[b*4+h]; 8 elems/thread.
// ---------------------------------------------------------------------------
__global__ __launch_bounds__(256)
void mean_heads(const unsigned short* __restrict__ UT, unsigned short* __restrict__ Ub)
{
    const long per = 1024L * 512;
    long e = ((long)blockIdx.x * 256 + threadIdx.x) * 8;
    long b = e / per; long r = e - b * per;
    const short8 v0 = *(const short8*)(UT + (b * 4 + 0) * per + r);
    const short8 v1 = *(const short8*)(UT + (b * 4 + 1) * per + r);
    const short8 v2 = *(const short8*)(UT + (b * 4 + 2) * per + r);
    const short8 v3 = *(const short8*)(UT + (b * 4 + 3) * per + r);
    short8 o;
    #pragma unroll
    for (int k = 0; k < 8; ++k) {
        float s = bf2f((unsigned short)v0[k]) + bf2f((unsigned short)v1[k])
                + bf2f((unsigned short)v2[k]) + bf2f((unsigned short)v3[k]);
        o[k] = (short)f2bf(s);
    }
    *(short8*)(Ub + b * per + r) = o;
}

// ---------------------------------------------------------------------------
extern "C" void kernel_launch(void* const* d_in, const int* in_sizes, int n_in,
                              void* d_out, int out_size, void* d_ws, size_t ws_size,
                              hipStream_t stream)
{
    const float* emb     = (const float*)d_in[0];  // [4][4096][512]
    const float* emb_all = (const float*)d_in[1];  // [4][4096][960]
    const float* Wq      = (const float*)d_in[2];  // [4][512][512]
    const float* Wk      = (const float*)d_in[3];  // [4][960][960]
    const float* Wv      = (const float*)d_in[4];  // [4][960][960]
    const float* Wo      = (const float*)d_in[5];  // [512][512]
    float* out = (float*)d_out;

    char* ws = (char*)d_ws;
    unsigned short* embT     = (unsigned short*)(ws);              // [b] 512x4096 tiled
    unsigned short* emb_allT = (unsigned short*)(ws + 16777216);   // [b] 1024x4096 tiled
    unsigned short* emb_allB = (unsigned short*)(ws + 50331648);   // [b][4096][960]
    unsigned short* WqB      = (unsigned short*)(ws + 81788928);   // [h][512][512]
    unsigned short* WkB      = (unsigned short*)(ws + 83886080);   // [h][1024][960]
    unsigned short* WvT      = (unsigned short*)(ws + 91750400);   // [h][1024][960]
    unsigned short* WoB      = (unsigned short*)(ws + 99614720);   // [512][512]
    unsigned short* GT       = (unsigned short*)(ws + 100139008);  // [b][1024][512]
    unsigned short* probs    = (unsigned short*)(ws + 104333312);  // [z][512][1024]
    float2* sc_part          = (float2*)(ws + 121110528);          // [16][32]
    unsigned short* partK    = (unsigned short*)(ws + 134217728);  // 16 MB bf16

    // region reuse (sequential liveness)
    unsigned short* S1  = embT;                             // embT dead after splitk
    unsigned short* SC  = emb_allT;                         // emb_allT dead after splitk
    unsigned short* UT  = (unsigned short*)(ws + 33554432); // 2nd half of emb_allT region
    unsigned short* UbT = GT;                               // GT dead after step 2
    unsigned short* W2  = embT;                             // S1 dead after step 3

    // ---- 0. all preps, one launch ----
    prep_all<<<12224, 256, 0, stream>>>(emb, emb_all, Wq, Wk, Wv, Wo,
                                        embT, emb_allT, emb_allB, WqB, WkB, WvT, WoB);

    // ---- 1. split-K (z = b*4+sp): partK[z] = emb_allT chunk x embT chunk^T ----
    //      TILED layout: lda/ldb = 64*4096 (row-tile stride); sa_bh/sb_bh =
    //      sp*16 k-tiles = 65536 elems.
    gemm_bt<unsigned short, false, true><<<512, 512, 0, stream>>>(
        emb_allT, embT, partK, nullptr, 4, 8, 1024, 262144, 262144, 512,
        1024L*4096, 65536, 512L*4096, 65536, 1024L*512, 4, 1.f);
    reduce_gt<<<1024, 256, 0, stream>>>(partK, GT);

    // ---- 2. S1[b,h] = Wq[h] x GT[b]^T  (M=512, N=1024, K=512) ----
    gemm_bt<unsigned short, false, false><<<512, 512, 0, stream>>>(
        WqB, GT, S1, nullptr, 8, 4, 512, 512, 512, 1024,
        0, 512L*512, 1024L*512, 0, 512L*1024, 4, 1.f);

    // ---- 3. SC[z] = S1[z] x WkB[h]^T (bf16 out) + fused stats partials ----
    gemm_bt<unsigned short, true, false><<<512, 512, 0, stream>>>(
        S1, WkB, SC, sc_part, 8, 4, 960, 1024, 960, 1024,
        4L*512*1024, 512L*1024, 0, 1024L*960, 512L*1024, 4, 1.f);

    // ---- 4. fused instance-norm + softmax (wave-per-row) ----
    norm_softmax<<<2048, 256, 0, stream>>>(SC, sc_part, probs);

    // ---- 5. UT[z] = WvT[h] x probs[z]^T * 0.25  (M=1024, N=512, K=960) ----
    gemm_bt<unsigned short, false, false><<<512, 512, 0, stream>>>(
        WvT, probs, UT, nullptr, 4, 8, 960, 960, 1024, 512,
        0, 1024L*960, 4L*512*1024, 512L*1024, 1024L*512, 4, 0.25f);

    // ---- 6. UbT[b] = sum_h UT[b,h] ----
    mean_heads<<<1024, 256, 0, stream>>>(UT, UbT);

    // ---- 7. W2[b] = WoB x UbT[b]^T  (M=512, N=1024, K=512) ----
    gemm_bt<unsigned short, false, false><<<128, 512, 0, stream>>>(
        WoB, UbT, W2, nullptr, 8, 4, 512, 512, 512, 1024,
        0, 0, 1024L*512, 0, 512L*1024, 1, 1.f);

    // ---- 8. out[b] = emb_allB[b] x W2[b]^T  (M=4096, N=512, K=960) ----
    gemm_bt<float, false, false><<<512, 512, 0, stream>>>(
        emb_allB, W2, out, nullptr, 4, 32, 960, 960, 1024, 512,
        4096L*960, 0, 512L*1024, 0, 4096L*512, 1, 1.f);
}